// Round 10
// baseline (1963.905 us; speedup 1.0000x reference)
//
#include <hip/hip_runtime.h>
#include <hip/hip_bf16.h>
#include <math.h>

typedef unsigned short u16;
typedef __attribute__((ext_vector_type(8))) short bf16x8;
typedef __attribute__((ext_vector_type(4))) float f32x4;

__device__ inline u16 f2b(float f) {
  __hip_bfloat16 h = __float2bfloat16(f);
  return *(u16*)&h;
}

// ---------------------------------------------------------------- prep ------
// builds: w1bh bf16 [32][256] (k=ky*32+kx*3+ch, /255 folded, zero-padded),
// w2bh bf16 [64][512], w3bh bf16 [64][576], fcwT bf16 [512][576],
// whhTi[(k*512+u)*4+g] (gate-interleaved float4 rows),
// hT0[k][b]=h0*m0 (transposed), cbuf[b][u]=c0*m0
__global__ void __launch_bounds__(256) prep_k(
    const float* __restrict__ w1, const float* __restrict__ w2,
    const float* __restrict__ w3, const float* __restrict__ fcw,
    const float* __restrict__ whh, const float* __restrict__ done,
    const float* __restrict__ h0, const float* __restrict__ c0,
    u16* __restrict__ w1bh, u16* __restrict__ w2bh, u16* __restrict__ w3bh,
    u16* __restrict__ fcwT, float* __restrict__ whhTi,
    float* __restrict__ hT0, float* __restrict__ cbuf) {
  int i = blockIdx.x * 256 + threadIdx.x;
  if (i < 8192) {  // w1bh[c][k] bf16, k=ky*32+(kx*3+ch), /255 folded
    int c = i >> 8, k = i & 255;
    int ky = k >> 5, rem = k & 31;
    float v = 0.f;
    if (rem < 24) {
      int kx = rem / 3, ch = rem - kx * 3;
      v = w1[((c * 3 + ch) * 8 + ky) * 8 + kx] * (1.0f / 255.0f);
    }
    w1bh[i] = f2b(v);
    return;
  }
  i -= 8192;
  if (i < 32768) {  // w2bh[c][k] bf16
    int c = i >> 9, k = i & 511;
    int ci = k & 31, kyx = k >> 5;
    int ky = kyx >> 2, kx = kyx & 3;
    w2bh[i] = f2b(w2[c * 512 + ci * 16 + ky * 4 + kx]);
    return;
  }
  i -= 32768;
  if (i < 36864) {  // w3bh[c][k] bf16, k=(ky*3+kx)*64+ci
    int c = i / 576, k = i - c * 576;
    int ci = k & 63, kyx = k >> 6;
    int ky = kyx / 3, kx = kyx - ky * 3;
    w3bh[i] = f2b(w3[((c * 64 + ci) * 3 + ky) * 3 + kx]);
    return;
  }
  i -= 36864;
  if (i < 294912) {  // fcwT[o][r], r = yx*64+c  (bf16)
    int o = i / 576, r = i - o * 576;
    int c = r & 63, yx = r >> 6;
    fcwT[i] = f2b(fcw[(c * 9 + yx) * 512 + o]);
    return;
  }
  i -= 294912;
  if (i < 1048576) {  // whhTi[(k*512+u)*4+g] = whh[(g*512+u)][k]
    int g = i & 3;
    int rest = i >> 2;
    int u = rest & 511;
    int k = rest >> 9;
    whhTi[i] = whh[((g * 512 + u) * 512) + k];
    return;
  }
  i -= 1048576;
  if (i < 32768) {
    int b = i & 63;  // layout [k][b]
    int k = i >> 6;
    hT0[i] = h0[b * 512 + k] * (1.0f - done[b]);
    return;
  }
  i -= 32768;
  if (i < 32768) {
    int b = i >> 9;  // layout [b][u]
    cbuf[i] = c0[i] * (1.0f - done[b]);
  }
}

// ---------------------------------------------------------------- conv1m ----
// Implicit-GEMM MFMA conv1: x[n][52][52][3] fp32 -> a1h bf16 [n][12][12][32].
__global__ void __launch_bounds__(256) conv1m_k(
    const float* __restrict__ x, const u16* __restrict__ w1bh,
    const float* __restrict__ b1, u16* __restrict__ a1h) {
  __shared__ u16 As[256 * 40];
  __shared__ u16 Bs[32 * 40];
  const int tid = threadIdx.x;
  const long bm = (long)blockIdx.x * 256;
  const int w = tid >> 6;
  const int lane = tid & 63;
  const int lr = lane & 15;
  const int lk = lane >> 4;
  const int wm = w * 64;
  const int r = (int)bm + tid;
  const int n = r / 144;
  const int p = r - n * 144;
  const int py = p / 12;
  const int px = p - py * 12;
  const long gbase = (long)n * 8112 + py * 624 + px * 12;
  f32x4 zero = {0.f, 0.f, 0.f, 0.f};
  f32x4 acc[4][2];
#pragma unroll
  for (int mi = 0; mi < 4; ++mi)
#pragma unroll
    for (int ni = 0; ni < 2; ++ni) acc[mi][ni] = zero;

  const ushort4 z4 = {0, 0, 0, 0};
  for (int ky = 0; ky < 8; ++ky) {
    const float* src = x + gbase + ky * 156;
    float4 v[6];
#pragma unroll
    for (int q = 0; q < 6; ++q) v[q] = *(const float4*)&src[q * 4];
    u16* dst = &As[tid * 40];
#pragma unroll
    for (int q = 0; q < 6; ++q) {
      ushort4 o;
      o.x = f2b(v[q].x); o.y = f2b(v[q].y);
      o.z = f2b(v[q].z); o.w = f2b(v[q].w);
      *(ushort4*)&dst[q * 4] = o;
    }
    *(ushort4*)&dst[24] = z4;
    *(ushort4*)&dst[28] = z4;
    if (tid < 128) {
      const int c = tid >> 2, q = tid & 3;
      *(uint4*)&Bs[c * 40 + q * 8] = *(const uint4*)&w1bh[c * 256 + ky * 32 + q * 8];
    }
    __syncthreads();
    bf16x8 af[4], bfr[2];
#pragma unroll
    for (int mi = 0; mi < 4; ++mi)
      af[mi] = *(const bf16x8*)&As[(wm + mi * 16 + lr) * 40 + lk * 8];
#pragma unroll
    for (int ni = 0; ni < 2; ++ni)
      bfr[ni] = *(const bf16x8*)&Bs[(ni * 16 + lr) * 40 + lk * 8];
#pragma unroll
    for (int mi = 0; mi < 4; ++mi)
#pragma unroll
      for (int ni = 0; ni < 2; ++ni)
        acc[mi][ni] = __builtin_amdgcn_mfma_f32_16x16x32_bf16(
            af[mi], bfr[ni], acc[mi][ni], 0, 0, 0);
    __syncthreads();
  }
#pragma unroll
  for (int ni = 0; ni < 2; ++ni) {
    float bv = b1[ni * 16 + lr];
#pragma unroll
    for (int mi = 0; mi < 4; ++mi) {
#pragma unroll
      for (int j = 0; j < 4; ++j) {
        long rg = bm + wm + mi * 16 + lk * 4 + j;
        float v = fmaxf(acc[mi][ni][j] + bv, 0.f);
        a1h[rg * 32 + ni * 16 + lr] = f2b(v);
      }
    }
  }
}

// ---------------------------------------------------------------- conv2m ----
// Implicit-GEMM MFMA conv2: a1h[n][12][12][32] -> a2h bf16 [n][5][5][64].
__global__ void __launch_bounds__(256) conv2m_k(
    const u16* __restrict__ a1h, const u16* __restrict__ w2bh,
    const float* __restrict__ b2, u16* __restrict__ a2h) {
  __shared__ u16 As[256 * 40];
  __shared__ u16 Bs[64 * 40];
  const int tid = threadIdx.x;
  const long bm = (long)blockIdx.x * 256;
  const int w = tid >> 6;
  const int lane = tid & 63;
  const int lr = lane & 15;
  const int lk = lane >> 4;
  const int wm = w * 64;
  const int r = (int)bm + tid;
  const int n = r / 25;
  const int p = r - n * 25;
  const int py = p / 5;
  const int px = p - py * 5;
  const int pbase = n * 4608 + (py * 24 + px * 2) * 32;
  f32x4 zero = {0.f, 0.f, 0.f, 0.f};
  f32x4 acc[4][4];
#pragma unroll
  for (int mi = 0; mi < 4; ++mi)
#pragma unroll
    for (int ni = 0; ni < 4; ++ni) acc[mi][ni] = zero;

  for (int ks = 0; ks < 16; ++ks) {  // ks = ky*4+kx
    const int koff = ((ks >> 2) * 12 + (ks & 3)) * 32;
#pragma unroll
    for (int q = 0; q < 4; ++q)
      *(uint4*)&As[tid * 40 + q * 8] = *(const uint4*)&a1h[pbase + koff + q * 8];
    {
      const int c = tid >> 2, q = tid & 3;
      *(uint4*)&Bs[c * 40 + q * 8] = *(const uint4*)&w2bh[c * 512 + ks * 32 + q * 8];
    }
    __syncthreads();
    bf16x8 af[4], bfr[4];
#pragma unroll
    for (int mi = 0; mi < 4; ++mi)
      af[mi] = *(const bf16x8*)&As[(wm + mi * 16 + lr) * 40 + lk * 8];
#pragma unroll
    for (int ni = 0; ni < 4; ++ni)
      bfr[ni] = *(const bf16x8*)&Bs[(ni * 16 + lr) * 40 + lk * 8];
#pragma unroll
    for (int mi = 0; mi < 4; ++mi)
#pragma unroll
      for (int ni = 0; ni < 4; ++ni)
        acc[mi][ni] = __builtin_amdgcn_mfma_f32_16x16x32_bf16(
            af[mi], bfr[ni], acc[mi][ni], 0, 0, 0);
    __syncthreads();
  }
#pragma unroll
  for (int ni = 0; ni < 4; ++ni) {
    float bv = b2[ni * 16 + lr];
#pragma unroll
    for (int mi = 0; mi < 4; ++mi) {
#pragma unroll
      for (int j = 0; j < 4; ++j) {
        long rg = bm + wm + mi * 16 + lk * 4 + j;
        float v = fmaxf(acc[mi][ni][j] + bv, 0.f);
        a2h[rg * 64 + ni * 16 + lr] = f2b(v);
      }
    }
  }
}

// ---------------------------------------------------------------- conv3m ----
// Implicit-GEMM MFMA conv3: a2h[n][5][5][64] -> a3h bf16 [n][9*64] (fc layout).
__global__ void __launch_bounds__(256) conv3m_k(
    const u16* __restrict__ a2h, const u16* __restrict__ w3bh,
    const float* __restrict__ b3, u16* __restrict__ a3h) {
  __shared__ u16 As[256 * 40];
  __shared__ u16 Bs[64 * 40];
  const int tid = threadIdx.x;
  const long bm = (long)blockIdx.x * 256;
  const int w = tid >> 6;
  const int lane = tid & 63;
  const int lr = lane & 15;
  const int lk = lane >> 4;
  const int wm = w * 64;
  const int r = (int)bm + tid;
  const int n = r / 9;
  const int p = r - n * 9;
  const int py = p / 3;
  const int px = p - py * 3;
  const int pbase = n * 1600 + (py * 5 + px) * 64;
  f32x4 zero = {0.f, 0.f, 0.f, 0.f};
  f32x4 acc[4][4];
#pragma unroll
  for (int mi = 0; mi < 4; ++mi)
#pragma unroll
    for (int ni = 0; ni < 4; ++ni) acc[mi][ni] = zero;

  for (int ks2 = 0; ks2 < 18; ++ks2) {
    const int tap = ks2 >> 1;
    const int ky = tap / 3, kx = tap - ky * 3;
    const int koff = (ky * 5 + kx) * 64 + (ks2 & 1) * 32;
#pragma unroll
    for (int q = 0; q < 4; ++q)
      *(uint4*)&As[tid * 40 + q * 8] = *(const uint4*)&a2h[pbase + koff + q * 8];
    {
      const int c = tid >> 2, q = tid & 3;
      *(uint4*)&Bs[c * 40 + q * 8] = *(const uint4*)&w3bh[c * 576 + ks2 * 32 + q * 8];
    }
    __syncthreads();
    bf16x8 af[4], bfr[4];
#pragma unroll
    for (int mi = 0; mi < 4; ++mi)
      af[mi] = *(const bf16x8*)&As[(wm + mi * 16 + lr) * 40 + lk * 8];
#pragma unroll
    for (int ni = 0; ni < 4; ++ni)
      bfr[ni] = *(const bf16x8*)&Bs[(ni * 16 + lr) * 40 + lk * 8];
#pragma unroll
    for (int mi = 0; mi < 4; ++mi)
#pragma unroll
      for (int ni = 0; ni < 4; ++ni)
        acc[mi][ni] = __builtin_amdgcn_mfma_f32_16x16x32_bf16(
            af[mi], bfr[ni], acc[mi][ni], 0, 0, 0);
    __syncthreads();
  }
#pragma unroll
  for (int ni = 0; ni < 4; ++ni) {
    float bv = b3[ni * 16 + lr];
#pragma unroll
    for (int mi = 0; mi < 4; ++mi) {
#pragma unroll
      for (int j = 0; j < 4; ++j) {
        long rg = bm + wm + mi * 16 + lk * 4 + j;
        float v = fmaxf(acc[mi][ni][j] + bv, 0.f);
        a3h[rg * 64 + ni * 16 + lr] = f2b(v);
      }
    }
  }
}

// ---------------------------------------------------------------- cast ------
__global__ void __launch_bounds__(256) cast_k(
    const float4* __restrict__ wihv, ushort4* __restrict__ wihh) {
  int i = blockIdx.x * 256 + threadIdx.x;
  if (i < 262144) {
    float4 v = wihv[i];
    ushort4 o;
    o.x = f2b(v.x); o.y = f2b(v.y); o.z = f2b(v.z); o.w = f2b(v.w);
    wihh[i] = o;
  }
}

// ---------------------------------------------------------------- mgemm -----
// bf16 MFMA GEMM: C[M][N] = A[M][K] * B[N][K]^T (+bias, opt relu).
__global__ void __launch_bounds__(256) mgemm_k(
    const u16* __restrict__ A, const u16* __restrict__ B,
    const float* __restrict__ bias, float* __restrict__ Cf,
    u16* __restrict__ Ch, const int K, const int N,
    const int RELU, const int OUTBF16) {
  __shared__ u16 As[128 * 40];
  __shared__ u16 Bs[128 * 40];
  const int tid = threadIdx.x;
  const long bm = (long)blockIdx.x * 128;
  const long bn = (long)blockIdx.y * 128;
  const int w = tid >> 6;
  const int lane = tid & 63;
  const int lr = lane & 15;
  const int lk = lane >> 4;
  const int wm = (w >> 1) * 64, wn = (w & 1) * 64;
  f32x4 zero = {0.f, 0.f, 0.f, 0.f};
  f32x4 acc[4][4];
#pragma unroll
  for (int mi = 0; mi < 4; ++mi)
#pragma unroll
    for (int ni = 0; ni < 4; ++ni) acc[mi][ni] = zero;

  for (int k0 = 0; k0 < K; k0 += 32) {
#pragma unroll
    for (int q = 0; q < 2; ++q) {
      int idx = tid * 2 + q;
      int row = idx >> 2, kq = (idx & 3) * 8;
      *(uint4*)&As[row * 40 + kq] = *(const uint4*)&A[(bm + row) * K + k0 + kq];
      *(uint4*)&Bs[row * 40 + kq] = *(const uint4*)&B[(bn + row) * K + k0 + kq];
    }
    __syncthreads();
    bf16x8 af[4], bfr[4];
#pragma unroll
    for (int mi = 0; mi < 4; ++mi)
      af[mi] = *(const bf16x8*)&As[(wm + mi * 16 + lr) * 40 + lk * 8];
#pragma unroll
    for (int ni = 0; ni < 4; ++ni)
      bfr[ni] = *(const bf16x8*)&Bs[(wn + ni * 16 + lr) * 40 + lk * 8];
#pragma unroll
    for (int mi = 0; mi < 4; ++mi)
#pragma unroll
      for (int ni = 0; ni < 4; ++ni)
        acc[mi][ni] = __builtin_amdgcn_mfma_f32_16x16x32_bf16(
            af[mi], bfr[ni], acc[mi][ni], 0, 0, 0);
    __syncthreads();
  }
#pragma unroll
  for (int ni = 0; ni < 4; ++ni) {
    float bv = bias[bn + wn + ni * 16 + lr];
#pragma unroll
    for (int mi = 0; mi < 4; ++mi) {
#pragma unroll
      for (int j = 0; j < 4; ++j) {
        long rg = bm + wm + mi * 16 + lk * 4 + j;
        long cg = bn + wn + ni * 16 + lr;
        float v = acc[mi][ni][j] + bv;
        if (RELU) v = fmaxf(v, 0.f);
        if (OUTBF16) Ch[rg * N + cg] = f2b(v);
        else Cf[rg * N + cg] = v;
      }
    }
  }
}

// ------------------------------------------------------------- lstm step ----
// ONE timestep per launch; kernel boundary provides cross-XCD visibility.
// 512 blocks (2/CU for latency hiding): xcd=bid&7, uslice=xcd*4+(bid>>7)
// (0..31, XCD-affine: each XCD's weight slice = 4 uslices = 512KB, L2-resident),
// bg=(bid>>3)&15 (16 groups of 4 batch rows). Thread: uu=tid&15, kc=tid>>4.
// Weights read as float4 (4 gates of (k,u) interleaved in whhTi) — coalesced.
__global__ void __launch_bounds__(256) lstm_step_k(
    const float* __restrict__ gx, const float* __restrict__ whhTi,
    const float* __restrict__ done, float* __restrict__ hT2,
    float* __restrict__ cbuf, float* __restrict__ hseq,
    float* __restrict__ outh, float* __restrict__ outc, const int t) {
  __shared__ float red[256][17];
  const int tid = threadIdx.x;
  const int bid = blockIdx.x;
  const int uslice = (bid & 7) * 4 + (bid >> 7);  // 0..31 (XCD-affine)
  const int bg = (bid >> 3) & 15;                 // 0..15
  const int uu = tid & 15;
  const int kc = tid >> 4;
  const int u = uslice * 16 + uu;
  const int b0 = bg * 4;

  const float* hTp = hT2 + (t & 1) * 32768;
  float acc[4][4];  // [gate][batch j]
#pragma unroll
  for (int g = 0; g < 4; ++g)
#pragma unroll
    for (int j = 0; j < 4; ++j) acc[g][j] = 0.f;
  const int kbeg = kc * 32;
#pragma unroll 8
  for (int kk = 0; kk < 32; ++kk) {
    const int k = kbeg + kk;
    float4 w4 = *(const float4*)&whhTi[(k * 512 + u) * 4];
    float4 hv = *(const float4*)&hTp[k * 64 + b0];
    acc[0][0] += w4.x * hv.x; acc[0][1] += w4.x * hv.y; acc[0][2] += w4.x * hv.z; acc[0][3] += w4.x * hv.w;
    acc[1][0] += w4.y * hv.x; acc[1][1] += w4.y * hv.y; acc[1][2] += w4.y * hv.z; acc[1][3] += w4.y * hv.w;
    acc[2][0] += w4.z * hv.x; acc[2][1] += w4.z * hv.y; acc[2][2] += w4.z * hv.z; acc[2][3] += w4.z * hv.w;
    acc[3][0] += w4.w * hv.x; acc[3][1] += w4.w * hv.y; acc[3][2] += w4.w * hv.z; acc[3][3] += w4.w * hv.w;
  }
#pragma unroll
  for (int g = 0; g < 4; ++g)
#pragma unroll
    for (int j = 0; j < 4; ++j) red[tid][g * 4 + j] = acc[g][j];
  __syncthreads();
  if (tid < 64) {
    const int fu = tid >> 2;   // 0..15 (hidden within slice)
    const int fb = tid & 3;    // 0..3  (batch within group)
    float s0 = 0.f, s1 = 0.f, s2 = 0.f, s3 = 0.f;
#pragma unroll
    for (int q = 0; q < 16; ++q) {
      const float* rp = red[q * 16 + fu];
      s0 += rp[fb]; s1 += rp[4 + fb]; s2 += rp[8 + fb]; s3 += rp[12 + fb];
    }
    const int b = b0 + fb;
    const int ug = uslice * 16 + fu;
    const int row = t * 64 + b;
    const float* gxr = gx + (long)row * 2048;
    float pi = s0 + gxr[ug];
    float pf = s1 + gxr[512 + ug];
    float pg_ = s2 + gxr[1024 + ug];
    float po = s3 + gxr[1536 + ug];
    float ig = 1.f / (1.f + expf(-pi));
    float fg = 1.f / (1.f + expf(-pf));
    float og = 1.f / (1.f + expf(-po));
    float gg = tanhf(pg_);
    float cn = fg * cbuf[b * 512 + ug] + ig * gg;
    float hn = og * tanhf(cn);
    hseq[(long)row * 512 + ug] = hn;
    if (t == 127) {
      outh[b * 512 + ug] = hn;
      outc[b * 512 + ug] = cn;
    } else {
      float mn = 1.f - done[(t + 1) * 64 + b];
      cbuf[b * 512 + ug] = cn * mn;
      hT2[((t + 1) & 1) * 32768 + ug * 64 + b] = hn * mn;
    }
  }
}

// ---------------------------------------------------------------- heads -----
__global__ void __launch_bounds__(256) heads_k(
    const float* __restrict__ hseq, const float* __restrict__ aw,
    const float* __restrict__ ab, const float* __restrict__ cw,
    const float* __restrict__ cb, const int* __restrict__ action,
    float* __restrict__ out) {
  const int lane = threadIdx.x & 63;
  const int wid = threadIdx.x >> 6;
  const int row = blockIdx.x * 4 + wid;
  const int j = lane & 15;
  const int kc = lane >> 4;
  const float* f = hseq + (long)row * 512;
  float acc = 0.f;
  if (j < 15) {
    for (int k = kc * 128; k < kc * 128 + 128; ++k) acc += f[k] * aw[k * 15 + j];
  } else {
    for (int k = kc * 128; k < kc * 128 + 128; ++k) acc += f[k] * cw[k];
  }
  acc += __shfl_xor(acc, 16);
  acc += __shfl_xor(acc, 32);
  float logit = (j < 15) ? acc + ab[j] : -1e30f;
  float m = logit;
#pragma unroll
  for (int off = 1; off < 16; off <<= 1) m = fmaxf(m, __shfl_xor(m, off));
  float p = (j < 15) ? expf(logit - m) : 0.f;
  float S = p;
#pragma unroll
  for (int off = 1; off < 16; off <<= 1) S += __shfl_xor(S, off);
  float logS = logf(S);
  float lp = logit - m - logS;
  float e = (j < 15) ? p * lp : 0.f;
  float es = e;
#pragma unroll
  for (int off = 1; off < 16; off <<= 1) es += __shfl_xor(es, off);
  float ent = -es / S;
  int a = action[row];
  float lpa = __shfl(lp, (lane & 48) | a);
  float val = __shfl(acc, (lane & 48) | 15) + cb[0];
  if (lane == 0) {
    out[row] = lpa;
    out[8192 + row] = ent;
    out[16384 + row] = val;
  }
}

// ---------------------------------------------------------------- host ------
extern "C" void kernel_launch(void* const* d_in, const int* in_sizes, int n_in,
                              void* d_out, int out_size, void* d_ws, size_t ws_size,
                              hipStream_t stream) {
  const float* x    = (const float*)d_in[0];
  const float* done = (const float*)d_in[1];
  const float* h0   = (const float*)d_in[2];
  const float* c0   = (const float*)d_in[3];
  const int*   act  = (const int*)d_in[4];
  const float* w1   = (const float*)d_in[5];
  const float* b1   = (const float*)d_in[6];
  const float* w2   = (const float*)d_in[7];
  const float* b2   = (const float*)d_in[8];
  const float* w3   = (const float*)d_in[9];
  const float* b3   = (const float*)d_in[10];
  const float* fcw  = (const float*)d_in[11];
  const float* fcb  = (const float*)d_in[12];
  const float* wih  = (const float*)d_in[13];
  const float* whh  = (const float*)d_in[14];
  const float* blst = (const float*)d_in[15];
  const float* aw   = (const float*)d_in[16];
  const float* ab   = (const float*)d_in[17];
  const float* cw   = (const float*)d_in[18];
  const float* cb   = (const float*)d_in[19];
  float* ws  = (float*)d_ws;
  float* out = (float*)d_out;

  u16*  a1h   = (u16*)ws;
  u16*  wihh  = (u16*)(ws + 4718592);     // 2048*512 bf16
  float* hseq = ws + 8912896;
  u16*  a2h   = (u16*)(ws + 37748736);    // 204800*64 bf16
  u16*  a3h   = (u16*)(ws + 44302336);    // 73728*64 bf16
  u16*  hidh  = (u16*)(ws + 46661632);    // 8192*512 bf16
  float* gxb  = ws + 50855936;
  u16*  w1bh  = (u16*)(ws + 67633152);    // 32*256 bf16
  u16*  w2bh  = (u16*)(ws + 67639296);    // 64*512 bf16
  u16*  w3bh  = (u16*)(ws + 67672064);    // 64*576 bf16
  u16*  fcwT  = (u16*)(ws + 67708928);    // 512*576 bf16
  float* whhTi= ws + 68003840;            // [(k*512+u)*4+g] 1M floats
  float* hT2  = ws + 69052416;            // double-buffered [2][512][64]
  float* cbuf = ws + 69117952;            // -> total 69150720 f = 277 MB

  hipLaunchKernelGGL(prep_k, dim3(5808), dim3(256), 0, stream,
                     w1, w2, w3, fcw, whh, done, h0, c0,
                     w1bh, w2bh, w3bh, fcwT, whhTi, hT2, cbuf);
  hipLaunchKernelGGL(conv1m_k, dim3(4608), dim3(256), 0, stream, x, w1bh, b1, a1h);
  hipLaunchKernelGGL(conv2m_k, dim3(800), dim3(256), 0, stream, a1h, w2bh, b2, a2h);
  hipLaunchKernelGGL(conv3m_k, dim3(288), dim3(256), 0, stream, a2h, w3bh, b3, a3h);
  hipLaunchKernelGGL(cast_k, dim3(1024), dim3(256), 0, stream,
                     (const float4*)wih, (ushort4*)wihh);
  hipLaunchKernelGGL(mgemm_k, dim3(64, 4), dim3(256), 0, stream,
                     a3h, fcwT, fcb, (float*)nullptr, hidh, 576, 512, 1, 1);
  hipLaunchKernelGGL(mgemm_k, dim3(64, 16), dim3(256), 0, stream,
                     hidh, wihh, blst, gxb, (u16*)nullptr, 512, 2048, 0, 0);
  for (int t = 0; t < 128; ++t) {
    hipLaunchKernelGGL(lstm_step_k, dim3(512), dim3(256), 0, stream,
                       gxb, whhTi, done, hT2, cbuf, hseq,
                       out + 24576, out + 57344, t);
  }
  hipLaunchKernelGGL(heads_k, dim3(2048), dim3(256), 0, stream,
                     hseq, aw, ab, cw, cb, act, out);
}

// Round 11
// 1220.329 us; speedup vs baseline: 1.6093x; 1.6093x over previous
//
#include <hip/hip_runtime.h>
#include <hip/hip_bf16.h>
#include <math.h>

typedef unsigned short u16;
typedef __attribute__((ext_vector_type(8))) short bf16x8;
typedef __attribute__((ext_vector_type(4))) float f32x4;

__device__ inline u16 f2b(float f) {
  __hip_bfloat16 h = __float2bfloat16(f);
  return *(u16*)&h;
}

// ---------------------------------------------------------------- prep ------
// builds: w1bh bf16 [32][256] (k=ky*32+kx*3+ch, /255 folded, zero-padded),
// w2bh bf16 [64][512], w3bh bf16 [64][576], fcwT bf16 [512][576],
// whhT[k][2048] (j = gate*512+u; round-9 verified layout),
// hT0[k][b]=h0*m0 (transposed), cbuf[b][u]=c0*m0
__global__ void __launch_bounds__(256) prep_k(
    const float* __restrict__ w1, const float* __restrict__ w2,
    const float* __restrict__ w3, const float* __restrict__ fcw,
    const float* __restrict__ whh, const float* __restrict__ done,
    const float* __restrict__ h0, const float* __restrict__ c0,
    u16* __restrict__ w1bh, u16* __restrict__ w2bh, u16* __restrict__ w3bh,
    u16* __restrict__ fcwT, float* __restrict__ whhT,
    float* __restrict__ hT0, float* __restrict__ cbuf) {
  int i = blockIdx.x * 256 + threadIdx.x;
  if (i < 8192) {  // w1bh[c][k] bf16, k=ky*32+(kx*3+ch), /255 folded
    int c = i >> 8, k = i & 255;
    int ky = k >> 5, rem = k & 31;
    float v = 0.f;
    if (rem < 24) {
      int kx = rem / 3, ch = rem - kx * 3;
      v = w1[((c * 3 + ch) * 8 + ky) * 8 + kx] * (1.0f / 255.0f);
    }
    w1bh[i] = f2b(v);
    return;
  }
  i -= 8192;
  if (i < 32768) {  // w2bh[c][k] bf16
    int c = i >> 9, k = i & 511;
    int ci = k & 31, kyx = k >> 5;
    int ky = kyx >> 2, kx = kyx & 3;
    w2bh[i] = f2b(w2[c * 512 + ci * 16 + ky * 4 + kx]);
    return;
  }
  i -= 32768;
  if (i < 36864) {  // w3bh[c][k] bf16, k=(ky*3+kx)*64+ci
    int c = i / 576, k = i - c * 576;
    int ci = k & 63, kyx = k >> 6;
    int ky = kyx / 3, kx = kyx - ky * 3;
    w3bh[i] = f2b(w3[((c * 64 + ci) * 3 + ky) * 3 + kx]);
    return;
  }
  i -= 36864;
  if (i < 294912) {  // fcwT[o][r], r = yx*64+c  (bf16)
    int o = i / 576, r = i - o * 576;
    int c = r & 63, yx = r >> 6;
    fcwT[i] = f2b(fcw[(c * 9 + yx) * 512 + o]);
    return;
  }
  i -= 294912;
  if (i < 1048576) {  // whhT[k][2048], j=gate*512+u  (round-9 layout)
    int j = i & 2047, k = i >> 11;
    whhT[i] = whh[j * 512 + k];
    return;
  }
  i -= 1048576;
  if (i < 32768) {
    int b = i & 63;  // layout [k][b]
    int k = i >> 6;
    hT0[i] = h0[b * 512 + k] * (1.0f - done[b]);
    return;
  }
  i -= 32768;
  if (i < 32768) {
    int b = i >> 9;  // layout [b][u]
    cbuf[i] = c0[i] * (1.0f - done[b]);
  }
}

// ---------------------------------------------------------------- conv1m ----
// Implicit-GEMM MFMA conv1: x[n][52][52][3] fp32 -> a1h bf16 [n][12][12][32].
__global__ void __launch_bounds__(256) conv1m_k(
    const float* __restrict__ x, const u16* __restrict__ w1bh,
    const float* __restrict__ b1, u16* __restrict__ a1h) {
  __shared__ u16 As[256 * 40];
  __shared__ u16 Bs[32 * 40];
  const int tid = threadIdx.x;
  const long bm = (long)blockIdx.x * 256;
  const int w = tid >> 6;
  const int lane = tid & 63;
  const int lr = lane & 15;
  const int lk = lane >> 4;
  const int wm = w * 64;
  const int r = (int)bm + tid;
  const int n = r / 144;
  const int p = r - n * 144;
  const int py = p / 12;
  const int px = p - py * 12;
  const long gbase = (long)n * 8112 + py * 624 + px * 12;
  f32x4 zero = {0.f, 0.f, 0.f, 0.f};
  f32x4 acc[4][2];
#pragma unroll
  for (int mi = 0; mi < 4; ++mi)
#pragma unroll
    for (int ni = 0; ni < 2; ++ni) acc[mi][ni] = zero;

  const ushort4 z4 = {0, 0, 0, 0};
  for (int ky = 0; ky < 8; ++ky) {
    const float* src = x + gbase + ky * 156;
    float4 v[6];
#pragma unroll
    for (int q = 0; q < 6; ++q) v[q] = *(const float4*)&src[q * 4];
    u16* dst = &As[tid * 40];
#pragma unroll
    for (int q = 0; q < 6; ++q) {
      ushort4 o;
      o.x = f2b(v[q].x); o.y = f2b(v[q].y);
      o.z = f2b(v[q].z); o.w = f2b(v[q].w);
      *(ushort4*)&dst[q * 4] = o;
    }
    *(ushort4*)&dst[24] = z4;
    *(ushort4*)&dst[28] = z4;
    if (tid < 128) {
      const int c = tid >> 2, q = tid & 3;
      *(uint4*)&Bs[c * 40 + q * 8] = *(const uint4*)&w1bh[c * 256 + ky * 32 + q * 8];
    }
    __syncthreads();
    bf16x8 af[4], bfr[2];
#pragma unroll
    for (int mi = 0; mi < 4; ++mi)
      af[mi] = *(const bf16x8*)&As[(wm + mi * 16 + lr) * 40 + lk * 8];
#pragma unroll
    for (int ni = 0; ni < 2; ++ni)
      bfr[ni] = *(const bf16x8*)&Bs[(ni * 16 + lr) * 40 + lk * 8];
#pragma unroll
    for (int mi = 0; mi < 4; ++mi)
#pragma unroll
      for (int ni = 0; ni < 2; ++ni)
        acc[mi][ni] = __builtin_amdgcn_mfma_f32_16x16x32_bf16(
            af[mi], bfr[ni], acc[mi][ni], 0, 0, 0);
    __syncthreads();
  }
#pragma unroll
  for (int ni = 0; ni < 2; ++ni) {
    float bv = b1[ni * 16 + lr];
#pragma unroll
    for (int mi = 0; mi < 4; ++mi) {
#pragma unroll
      for (int j = 0; j < 4; ++j) {
        long rg = bm + wm + mi * 16 + lk * 4 + j;
        float v = fmaxf(acc[mi][ni][j] + bv, 0.f);
        a1h[rg * 32 + ni * 16 + lr] = f2b(v);
      }
    }
  }
}

// ---------------------------------------------------------------- conv2m ----
// Implicit-GEMM MFMA conv2: a1h[n][12][12][32] -> a2h bf16 [n][5][5][64].
__global__ void __launch_bounds__(256) conv2m_k(
    const u16* __restrict__ a1h, const u16* __restrict__ w2bh,
    const float* __restrict__ b2, u16* __restrict__ a2h) {
  __shared__ u16 As[256 * 40];
  __shared__ u16 Bs[64 * 40];
  const int tid = threadIdx.x;
  const long bm = (long)blockIdx.x * 256;
  const int w = tid >> 6;
  const int lane = tid & 63;
  const int lr = lane & 15;
  const int lk = lane >> 4;
  const int wm = w * 64;
  const int r = (int)bm + tid;
  const int n = r / 25;
  const int p = r - n * 25;
  const int py = p / 5;
  const int px = p - py * 5;
  const int pbase = n * 4608 + (py * 24 + px * 2) * 32;
  f32x4 zero = {0.f, 0.f, 0.f, 0.f};
  f32x4 acc[4][4];
#pragma unroll
  for (int mi = 0; mi < 4; ++mi)
#pragma unroll
    for (int ni = 0; ni < 4; ++ni) acc[mi][ni] = zero;

  for (int ks = 0; ks < 16; ++ks) {  // ks = ky*4+kx
    const int koff = ((ks >> 2) * 12 + (ks & 3)) * 32;
#pragma unroll
    for (int q = 0; q < 4; ++q)
      *(uint4*)&As[tid * 40 + q * 8] = *(const uint4*)&a1h[pbase + koff + q * 8];
    {
      const int c = tid >> 2, q = tid & 3;
      *(uint4*)&Bs[c * 40 + q * 8] = *(const uint4*)&w2bh[c * 512 + ks * 32 + q * 8];
    }
    __syncthreads();
    bf16x8 af[4], bfr[4];
#pragma unroll
    for (int mi = 0; mi < 4; ++mi)
      af[mi] = *(const bf16x8*)&As[(wm + mi * 16 + lr) * 40 + lk * 8];
#pragma unroll
    for (int ni = 0; ni < 4; ++ni)
      bfr[ni] = *(const bf16x8*)&Bs[(ni * 16 + lr) * 40 + lk * 8];
#pragma unroll
    for (int mi = 0; mi < 4; ++mi)
#pragma unroll
      for (int ni = 0; ni < 4; ++ni)
        acc[mi][ni] = __builtin_amdgcn_mfma_f32_16x16x32_bf16(
            af[mi], bfr[ni], acc[mi][ni], 0, 0, 0);
    __syncthreads();
  }
#pragma unroll
  for (int ni = 0; ni < 4; ++ni) {
    float bv = b2[ni * 16 + lr];
#pragma unroll
    for (int mi = 0; mi < 4; ++mi) {
#pragma unroll
      for (int j = 0; j < 4; ++j) {
        long rg = bm + wm + mi * 16 + lk * 4 + j;
        float v = fmaxf(acc[mi][ni][j] + bv, 0.f);
        a2h[rg * 64 + ni * 16 + lr] = f2b(v);
      }
    }
  }
}

// ---------------------------------------------------------------- conv3m ----
// Implicit-GEMM MFMA conv3: a2h[n][5][5][64] -> a3h bf16 [n][9*64] (fc layout).
__global__ void __launch_bounds__(256) conv3m_k(
    const u16* __restrict__ a2h, const u16* __restrict__ w3bh,
    const float* __restrict__ b3, u16* __restrict__ a3h) {
  __shared__ u16 As[256 * 40];
  __shared__ u16 Bs[64 * 40];
  const int tid = threadIdx.x;
  const long bm = (long)blockIdx.x * 256;
  const int w = tid >> 6;
  const int lane = tid & 63;
  const int lr = lane & 15;
  const int lk = lane >> 4;
  const int wm = w * 64;
  const int r = (int)bm + tid;
  const int n = r / 9;
  const int p = r - n * 9;
  const int py = p / 3;
  const int px = p - py * 3;
  const int pbase = n * 1600 + (py * 5 + px) * 64;
  f32x4 zero = {0.f, 0.f, 0.f, 0.f};
  f32x4 acc[4][4];
#pragma unroll
  for (int mi = 0; mi < 4; ++mi)
#pragma unroll
    for (int ni = 0; ni < 4; ++ni) acc[mi][ni] = zero;

  for (int ks2 = 0; ks2 < 18; ++ks2) {
    const int tap = ks2 >> 1;
    const int ky = tap / 3, kx = tap - ky * 3;
    const int koff = (ky * 5 + kx) * 64 + (ks2 & 1) * 32;
#pragma unroll
    for (int q = 0; q < 4; ++q)
      *(uint4*)&As[tid * 40 + q * 8] = *(const uint4*)&a2h[pbase + koff + q * 8];
    {
      const int c = tid >> 2, q = tid & 3;
      *(uint4*)&Bs[c * 40 + q * 8] = *(const uint4*)&w3bh[c * 576 + ks2 * 32 + q * 8];
    }
    __syncthreads();
    bf16x8 af[4], bfr[4];
#pragma unroll
    for (int mi = 0; mi < 4; ++mi)
      af[mi] = *(const bf16x8*)&As[(wm + mi * 16 + lr) * 40 + lk * 8];
#pragma unroll
    for (int ni = 0; ni < 4; ++ni)
      bfr[ni] = *(const bf16x8*)&Bs[(ni * 16 + lr) * 40 + lk * 8];
#pragma unroll
    for (int mi = 0; mi < 4; ++mi)
#pragma unroll
      for (int ni = 0; ni < 4; ++ni)
        acc[mi][ni] = __builtin_amdgcn_mfma_f32_16x16x32_bf16(
            af[mi], bfr[ni], acc[mi][ni], 0, 0, 0);
    __syncthreads();
  }
#pragma unroll
  for (int ni = 0; ni < 4; ++ni) {
    float bv = b3[ni * 16 + lr];
#pragma unroll
    for (int mi = 0; mi < 4; ++mi) {
#pragma unroll
      for (int j = 0; j < 4; ++j) {
        long rg = bm + wm + mi * 16 + lk * 4 + j;
        float v = fmaxf(acc[mi][ni][j] + bv, 0.f);
        a3h[rg * 64 + ni * 16 + lr] = f2b(v);
      }
    }
  }
}

// ---------------------------------------------------------------- cast ------
__global__ void __launch_bounds__(256) cast_k(
    const float4* __restrict__ wihv, ushort4* __restrict__ wihh) {
  int i = blockIdx.x * 256 + threadIdx.x;
  if (i < 262144) {
    float4 v = wihv[i];
    ushort4 o;
    o.x = f2b(v.x); o.y = f2b(v.y); o.z = f2b(v.z); o.w = f2b(v.w);
    wihh[i] = o;
  }
}

// ---------------------------------------------------------------- mgemm -----
// bf16 MFMA GEMM: C[M][N] = A[M][K] * B[N][K]^T (+bias, opt relu).
__global__ void __launch_bounds__(256) mgemm_k(
    const u16* __restrict__ A, const u16* __restrict__ B,
    const float* __restrict__ bias, float* __restrict__ Cf,
    u16* __restrict__ Ch, const int K, const int N,
    const int RELU, const int OUTBF16) {
  __shared__ u16 As[128 * 40];
  __shared__ u16 Bs[128 * 40];
  const int tid = threadIdx.x;
  const long bm = (long)blockIdx.x * 128;
  const long bn = (long)blockIdx.y * 128;
  const int w = tid >> 6;
  const int lane = tid & 63;
  const int lr = lane & 15;
  const int lk = lane >> 4;
  const int wm = (w >> 1) * 64, wn = (w & 1) * 64;
  f32x4 zero = {0.f, 0.f, 0.f, 0.f};
  f32x4 acc[4][4];
#pragma unroll
  for (int mi = 0; mi < 4; ++mi)
#pragma unroll
    for (int ni = 0; ni < 4; ++ni) acc[mi][ni] = zero;

  for (int k0 = 0; k0 < K; k0 += 32) {
#pragma unroll
    for (int q = 0; q < 2; ++q) {
      int idx = tid * 2 + q;
      int row = idx >> 2, kq = (idx & 3) * 8;
      *(uint4*)&As[row * 40 + kq] = *(const uint4*)&A[(bm + row) * K + k0 + kq];
      *(uint4*)&Bs[row * 40 + kq] = *(const uint4*)&B[(bn + row) * K + k0 + kq];
    }
    __syncthreads();
    bf16x8 af[4], bfr[4];
#pragma unroll
    for (int mi = 0; mi < 4; ++mi)
      af[mi] = *(const bf16x8*)&As[(wm + mi * 16 + lr) * 40 + lk * 8];
#pragma unroll
    for (int ni = 0; ni < 4; ++ni)
      bfr[ni] = *(const bf16x8*)&Bs[(wn + ni * 16 + lr) * 40 + lk * 8];
#pragma unroll
    for (int mi = 0; mi < 4; ++mi)
#pragma unroll
      for (int ni = 0; ni < 4; ++ni)
        acc[mi][ni] = __builtin_amdgcn_mfma_f32_16x16x32_bf16(
            af[mi], bfr[ni], acc[mi][ni], 0, 0, 0);
    __syncthreads();
  }
#pragma unroll
  for (int ni = 0; ni < 4; ++ni) {
    float bv = bias[bn + wn + ni * 16 + lr];
#pragma unroll
    for (int mi = 0; mi < 4; ++mi) {
#pragma unroll
      for (int j = 0; j < 4; ++j) {
        long rg = bm + wm + mi * 16 + lk * 4 + j;
        long cg = bn + wn + ni * 16 + lr;
        float v = acc[mi][ni][j] + bv;
        if (RELU) v = fmaxf(v, 0.f);
        if (OUTBF16) Ch[rg * N + cg] = f2b(v);
        else Cf[rg * N + cg] = v;
      }
    }
  }
}

// ------------------------------------------------------------- lstm step ----
// ONE timestep per launch; kernel boundary provides cross-XCD visibility.
// Round-9's verified dataflow and whhT[k][2048] addressing, extended from
// 256 to 512 threads for occupancy (8 waves/CU vs 4): kc = tid>>4 in [0,32),
// each thread covers a 16-k chunk (kbeg=kc*16); red[512][37]; finalize
// threads 0..127 sum q=0..31 (rows q*16+uu = all kc-chunks of uu).
// XCD swizzle unchanged: uslice=(bid&7)*4+(bid>>6), bg=(bid>>3)&7.
__global__ void __launch_bounds__(512) lstm_step_k(
    const float* __restrict__ gx, const float* __restrict__ whhT,
    const float* __restrict__ done, float* __restrict__ hT2,
    float* __restrict__ cbuf, float* __restrict__ hseq,
    float* __restrict__ outh, float* __restrict__ outc, const int t) {
  __shared__ float red[512][37];
  const int tid = threadIdx.x;
  const int bid = blockIdx.x;
  const int uslice = (bid & 7) * 4 + (bid >> 6);  // 0..31 (XCD-affine)
  const int bg = (bid >> 3) & 7;                  // 0..7
  const int uu = tid & 15;
  const int kc = tid >> 4;                        // 0..31
  const int u = uslice * 16 + uu;
  const int b0 = bg * 8;
  const int fbl = tid >> 4;

  const float* hTp = hT2 + (t & 1) * 32768;
  float a0[8] = {0.f}, a1_[8] = {0.f}, a2_[8] = {0.f}, a3_[8] = {0.f};
  const int kbeg = kc * 16;
#pragma unroll 4
  for (int kk = 0; kk < 16; ++kk) {
    int k = kbeg + kk;
    const float* wr = whhT + k * 2048;
    float w0 = wr[u];
    float w1 = wr[u + 512];
    float w2 = wr[u + 1024];
    float w3 = wr[u + 1536];
    float hv[8];
    *(float4*)&hv[0] = *(const float4*)&hTp[k * 64 + b0];
    *(float4*)&hv[4] = *(const float4*)&hTp[k * 64 + b0 + 4];
#pragma unroll
    for (int j = 0; j < 8; ++j) {
      a0[j] += w0 * hv[j]; a1_[j] += w1 * hv[j];
      a2_[j] += w2 * hv[j]; a3_[j] += w3 * hv[j];
    }
  }
#pragma unroll
  for (int j = 0; j < 8; ++j) {
    red[tid][j] = a0[j];       red[tid][8 + j] = a1_[j];
    red[tid][16 + j] = a2_[j]; red[tid][24 + j] = a3_[j];
  }
  __syncthreads();
  if (fbl < 8) {
    float s0 = 0.f, s1 = 0.f, s2 = 0.f, s3 = 0.f;
#pragma unroll
    for (int q = 0; q < 32; ++q) {
      const float* rp = red[q * 16 + uu];
      s0 += rp[fbl]; s1 += rp[8 + fbl]; s2 += rp[16 + fbl]; s3 += rp[24 + fbl];
    }
    const int b = b0 + fbl;
    const int ug = uslice * 16 + uu;
    const int row = t * 64 + b;
    const float* gxr = gx + (long)row * 2048;
    float pi = s0 + gxr[ug];
    float pf = s1 + gxr[512 + ug];
    float pg_ = s2 + gxr[1024 + ug];
    float po = s3 + gxr[1536 + ug];
    float ig = 1.f / (1.f + expf(-pi));
    float fg = 1.f / (1.f + expf(-pf));
    float og = 1.f / (1.f + expf(-po));
    float gg = tanhf(pg_);
    float cn = fg * cbuf[b * 512 + ug] + ig * gg;
    float hn = og * tanhf(cn);
    hseq[(long)row * 512 + ug] = hn;
    if (t == 127) {
      outh[b * 512 + ug] = hn;
      outc[b * 512 + ug] = cn;
    } else {
      float mn = 1.f - done[(t + 1) * 64 + b];
      cbuf[b * 512 + ug] = cn * mn;
      hT2[((t + 1) & 1) * 32768 + ug * 64 + b] = hn * mn;
    }
  }
}

// ---------------------------------------------------------------- heads -----
__global__ void __launch_bounds__(256) heads_k(
    const float* __restrict__ hseq, const float* __restrict__ aw,
    const float* __restrict__ ab, const float* __restrict__ cw,
    const float* __restrict__ cb, const int* __restrict__ action,
    float* __restrict__ out) {
  const int lane = threadIdx.x & 63;
  const int wid = threadIdx.x >> 6;
  const int row = blockIdx.x * 4 + wid;
  const int j = lane & 15;
  const int kc = lane >> 4;
  const float* f = hseq + (long)row * 512;
  float acc = 0.f;
  if (j < 15) {
    for (int k = kc * 128; k < kc * 128 + 128; ++k) acc += f[k] * aw[k * 15 + j];
  } else {
    for (int k = kc * 128; k < kc * 128 + 128; ++k) acc += f[k] * cw[k];
  }
  acc += __shfl_xor(acc, 16);
  acc += __shfl_xor(acc, 32);
  float logit = (j < 15) ? acc + ab[j] : -1e30f;
  float m = logit;
#pragma unroll
  for (int off = 1; off < 16; off <<= 1) m = fmaxf(m, __shfl_xor(m, off));
  float p = (j < 15) ? expf(logit - m) : 0.f;
  float S = p;
#pragma unroll
  for (int off = 1; off < 16; off <<= 1) S += __shfl_xor(S, off);
  float logS = logf(S);
  float lp = logit - m - logS;
  float e = (j < 15) ? p * lp : 0.f;
  float es = e;
#pragma unroll
  for (int off = 1; off < 16; off <<= 1) es += __shfl_xor(es, off);
  float ent = -es / S;
  int a = action[row];
  float lpa = __shfl(lp, (lane & 48) | a);
  float val = __shfl(acc, (lane & 48) | 15) + cb[0];
  if (lane == 0) {
    out[row] = lpa;
    out[8192 + row] = ent;
    out[16384 + row] = val;
  }
}

// ---------------------------------------------------------------- host ------
extern "C" void kernel_launch(void* const* d_in, const int* in_sizes, int n_in,
                              void* d_out, int out_size, void* d_ws, size_t ws_size,
                              hipStream_t stream) {
  const float* x    = (const float*)d_in[0];
  const float* done = (const float*)d_in[1];
  const float* h0   = (const float*)d_in[2];
  const float* c0   = (const float*)d_in[3];
  const int*   act  = (const int*)d_in[4];
  const float* w1   = (const float*)d_in[5];
  const float* b1   = (const float*)d_in[6];
  const float* w2   = (const float*)d_in[7];
  const float* b2   = (const float*)d_in[8];
  const float* w3   = (const float*)d_in[9];
  const float* b3   = (const float*)d_in[10];
  const float* fcw  = (const float*)d_in[11];
  const float* fcb  = (const float*)d_in[12];
  const float* wih  = (const float*)d_in[13];
  const float* whh  = (const float*)d_in[14];
  const float* blst = (const float*)d_in[15];
  const float* aw   = (const float*)d_in[16];
  const float* ab   = (const float*)d_in[17];
  const float* cw   = (const float*)d_in[18];
  const float* cb   = (const float*)d_in[19];
  float* ws  = (float*)d_ws;
  float* out = (float*)d_out;

  u16*  a1h   = (u16*)ws;
  u16*  wihh  = (u16*)(ws + 4718592);     // 2048*512 bf16
  float* hseq = ws + 8912896;
  u16*  a2h   = (u16*)(ws + 37748736);    // 204800*64 bf16
  u16*  a3h   = (u16*)(ws + 44302336);    // 73728*64 bf16
  u16*  hidh  = (u16*)(ws + 46661632);    // 8192*512 bf16
  float* gxb  = ws + 50855936;
  u16*  w1bh  = (u16*)(ws + 67633152);    // 32*256 bf16
  u16*  w2bh  = (u16*)(ws + 67639296);    // 64*512 bf16
  u16*  w3bh  = (u16*)(ws + 67672064);    // 64*576 bf16
  u16*  fcwT  = (u16*)(ws + 67708928);    // 512*576 bf16
  float* whhT = ws + 68003840;            // [512 k][2048] fp32
  float* hT2  = ws + 69052416;            // double-buffered [2][512][64]
  float* cbuf = ws + 69117952;            // -> total 69150720 f = 277 MB

  hipLaunchKernelGGL(prep_k, dim3(5808), dim3(256), 0, stream,
                     w1, w2, w3, fcw, whh, done, h0, c0,
                     w1bh, w2bh, w3bh, fcwT, whhT, hT2, cbuf);
  hipLaunchKernelGGL(conv1m_k, dim3(4608), dim3(256), 0, stream, x, w1bh, b1, a1h);
  hipLaunchKernelGGL(conv2m_k, dim3(800), dim3(256), 0, stream, a1h, w2bh, b2, a2h);
  hipLaunchKernelGGL(conv3m_k, dim3(288), dim3(256), 0, stream, a2h, w3bh, b3, a3h);
  hipLaunchKernelGGL(cast_k, dim3(1024), dim3(256), 0, stream,
                     (const float4*)wih, (ushort4*)wihh);
  hipLaunchKernelGGL(mgemm_k, dim3(64, 4), dim3(256), 0, stream,
                     a3h, fcwT, fcb, (float*)nullptr, hidh, 576, 512, 1, 1);
  hipLaunchKernelGGL(mgemm_k, dim3(64, 16), dim3(256), 0, stream,
                     hidh, wihh, blst, gxb, (u16*)nullptr, 512, 2048, 0, 0);
  for (int t = 0; t < 128; ++t) {
    hipLaunchKernelGGL(lstm_step_k, dim3(256), dim3(512), 0, stream,
                       gxb, whhT, done, hT2, cbuf, hseq,
                       out + 24576, out + 57344, t);
  }
  hipLaunchKernelGGL(heads_k, dim3(2048), dim3(256), 0, stream,
                     hseq, aw, ab, cw, cb, act, out);
}